// Round 2
// baseline (1216.988 us; speedup 1.0000x reference)
//
#include <hip/hip_runtime.h>
#include <math.h>

#define IMG 768
#define TILE 32
#define KFUSE 4
#define IT (TILE + 2 * KFUSE)   // 40x40 input tile
#define NB (IMG / TILE)         // 24 -> 576 blocks
#define NITER 64
#define RES_SCALE 0.1f
#define NTHREADS 512

// Exact GELU: 0.5*x*(1+erf(x/sqrt(2))), erf via Abramowitz-Stegun 7.1.26
// (|abs err| < 1.5e-7 over full range), branchless, hw rcp + exp2.
__device__ __forceinline__ float gelu_exact(float x) {
    float t = fabsf(x) * 0.70710678118654752f;
    float kk = __builtin_amdgcn_rcpf(fmaf(0.3275911f, t, 1.0f));
    float p = fmaf(1.061405429f, kk, -1.453152027f);
    p = fmaf(p, kk, 1.421413741f);
    p = fmaf(p, kk, -0.284496736f);
    p = fmaf(p, kk, 0.254829592f);
    p *= kk;
    float e = __builtin_amdgcn_exp2f(-t * t * 1.4426950408889634f);
    float r = fmaf(-e, p, 1.0f);   // erf(|x|/sqrt2) in [0,1)
    float es = copysignf(r, x);
    return 0.5f * x * (1.0f + es);
}

__global__ void resize_bilinear(const float* __restrict__ seed, float* __restrict__ out) {
    int idx = blockIdx.x * blockDim.x + threadIdx.x;
    if (idx >= IMG * IMG) return;
    int i = idx / IMG, j = idx - i * IMG;
    // half-pixel centers, align_corners=False; edge renormalization == clamp
    float sy = (i + 0.5f) * (8.0f / 768.0f) - 0.5f;
    float sx = (j + 0.5f) * (8.0f / 768.0f) - 0.5f;
    float fy = floorf(sy), fx = floorf(sx);
    float wy = sy - fy, wx = sx - fx;
    int y0 = (int)fy, x0 = (int)fx;
    int y0c = min(max(y0, 0), 7), y1c = min(max(y0 + 1, 0), 7);
    int x0c = min(max(x0, 0), 7), x1c = min(max(x0 + 1, 0), 7);
    float v00 = seed[y0c * 8 + x0c], v01 = seed[y0c * 8 + x1c];
    float v10 = seed[y1c * 8 + x0c], v11 = seed[y1c * 8 + x1c];
    float top = v00 + wx * (v01 - v00);
    float bot = v10 + wx * (v11 - v10);
    out[idx] = top + wy * (bot - top);
}

// KFUSE residual iterations fused per launch; shrinking-halo LDS tiles.
// Single-pass per-channel conv+GELU accumulate (no h[] array -> no spills);
// per-channel wave-uniform saturation fast path (erf saturates for |h|>5.56).
__global__ __launch_bounds__(NTHREADS, 1) void fused_steps(
        const float* __restrict__ xin, float* __restrict__ xout,
        const float* __restrict__ w1, const float* __restrict__ b1,
        const float* __restrict__ w2, const float* __restrict__ b2) {
    __shared__ float buf[2][IT * IT];
    const int tid = threadIdx.x;
    const int bx = blockIdx.x % NB, by = blockIdx.x / NB;
    const int gx0 = bx * TILE - KFUSE, gy0 = by * TILE - KFUSE;

    // stage 40x40 input tile (zero outside image = conv 'SAME' zero pad)
    for (int p = tid; p < IT * IT; p += NTHREADS) {
        int r = p / IT, c = p - r * IT;
        int gy = gy0 + r, gx = gx0 + c;
        float v = 0.0f;
        if (gy >= 0 && gy < IMG && gx >= 0 && gx < IMG) v = xin[gy * IMG + gx];
        buf[0][p] = v;
    }
    __syncthreads();

    const float b2v = b2[0];
#pragma unroll
    for (int j = 0; j < KFUSE; ++j) {
        const int S = IT - 2 - 2 * j;     // valid output region this step
        const int off = j + 1;
        const int cur = j & 1, nxt = cur ^ 1;
        const float* src = &buf[cur][0];
        float* dst = &buf[nxt][0];
        for (int p = tid; p < S * S; p += NTHREADS) {
            int rr = p / S;                // S is compile-time (unrolled j)
            int r = off + rr, c = off + (p - rr * S);
            float n0 = src[(r - 1) * IT + (c - 1)];
            float n1 = src[(r - 1) * IT + c];
            float n2 = src[(r - 1) * IT + (c + 1)];
            float n3 = src[r * IT + (c - 1)];
            float n4 = src[r * IT + c];
            float n5 = src[r * IT + (c + 1)];
            float n6 = src[(r + 1) * IT + (c - 1)];
            float n7 = src[(r + 1) * IT + c];
            float n8 = src[(r + 1) * IT + (c + 1)];
            float y = b2v;
#pragma unroll
            for (int cc = 0; cc < 16; ++cc) {
                const float* wc = &w1[cc * 9];   // uniform -> s_load
                float a = b1[cc];
                a = fmaf(wc[0], n0, a);
                a = fmaf(wc[1], n1, a);
                a = fmaf(wc[2], n2, a);
                a = fmaf(wc[3], n3, a);
                a = fmaf(wc[4], n4, a);
                a = fmaf(wc[5], n5, a);
                a = fmaf(wc[6], n6, a);
                a = fmaf(wc[7], n7, a);
                a = fmaf(wc[8], n8, a);
                // fp32 erf saturates to +-1 for |a| >= ~5.56 -> exact relu,
                // wave-uniform per-channel branch (values grow ~1e6 over iters)
                if (__all(fabsf(a) > 5.7f)) {
                    y = fmaf(w2[cc], fmaxf(a, 0.0f), y);
                } else {
                    y = fmaf(w2[cc], gelu_exact(a), y);
                }
            }
            int gy = gy0 + r, gx = gx0 + c;
            bool inimg = (gy >= 0) && (gy < IMG) && (gx >= 0) && (gx < IMG);
            // ghost pixels outside image stay 0 every iteration (zero padding)
            dst[r * IT + c] = inimg ? fmaf(RES_SCALE, y, n4) : 0.0f;
        }
        __syncthreads();
    }

    const int fin = KFUSE & 1;  // == 0
    for (int p = tid; p < TILE * TILE; p += NTHREADS) {
        int r = p / TILE, c = p - (p / TILE) * TILE;
        xout[(gy0 + KFUSE + r) * IMG + (gx0 + KFUSE + c)] =
            buf[fin][(KFUSE + r) * IT + (KFUSE + c)];
    }
}

extern "C" void kernel_launch(void* const* d_in, const int* in_sizes, int n_in,
                              void* d_out, int out_size, void* d_ws, size_t ws_size,
                              hipStream_t stream) {
    const float* seed = (const float*)d_in[0];
    const float* w1   = (const float*)d_in[1];
    const float* b1   = (const float*)d_in[2];
    const float* w2   = (const float*)d_in[3];
    const float* b2   = (const float*)d_in[4];
    // d_in[5]/d_in[6] are rows/cols = 768/768 (fixed by setup_inputs)

    float* out = (float*)d_out;
    float* ws  = (float*)d_ws;   // second ping-pong buffer (2.36 MB)

    resize_bilinear<<<(IMG * IMG + 255) / 256, 256, 0, stream>>>(seed, out);

    float* a = out;
    float* b = ws;
    for (int it = 0; it < NITER; it += KFUSE) {   // 16 launches, even -> ends in d_out
        fused_steps<<<NB * NB, NTHREADS, 0, stream>>>(a, b, w1, b1, w2, b2);
        float* t = a; a = b; b = t;
    }
}

// Round 3
// 661.682 us; speedup vs baseline: 1.8392x; 1.8392x over previous
//
#include <hip/hip_runtime.h>
#include <math.h>

#define IMG 768
#define TX 48
#define TY 24
#define KFUSE 4
#define ITX (TX + 2 * KFUSE)   // 56
#define ITY (TY + 2 * KFUSE)   // 32
#define NBX (IMG / TX)         // 16
#define NBY (IMG / TY)         // 32 -> 512 blocks = 2/CU exactly
#define NITER 64
#define RES_SCALE 0.1f
#define NT 512

// Exact GELU: 0.5*x*(1+erf(x/sqrt(2))), erf via Abramowitz-Stegun 7.1.26
// (|abs err| < 1.5e-7 over full range), branchless, hw rcp + exp2.
// Saturates gracefully for large |x| (exp2(-big)=0), so it is valid at any x.
__device__ __forceinline__ float gelu_exact(float x) {
    float t = fabsf(x) * 0.70710678118654752f;
    float kk = __builtin_amdgcn_rcpf(fmaf(0.3275911f, t, 1.0f));
    float p = fmaf(1.061405429f, kk, -1.453152027f);
    p = fmaf(p, kk, 1.421413741f);
    p = fmaf(p, kk, -0.284496736f);
    p = fmaf(p, kk, 0.254829592f);
    p *= kk;
    float e = __builtin_amdgcn_exp2f(-t * t * 1.4426950408889634f);
    float r = fmaf(-e, p, 1.0f);   // erf(|x|/sqrt2) in [0,1]
    float es = copysignf(r, x);
    return 0.5f * x * (1.0f + es);
}

__global__ void resize_bilinear(const float* __restrict__ seed, float* __restrict__ out) {
    int idx = blockIdx.x * blockDim.x + threadIdx.x;
    if (idx >= IMG * IMG) return;
    int i = idx / IMG, j = idx - i * IMG;
    // half-pixel centers, align_corners=False; edge renormalization == clamp
    float sy = (i + 0.5f) * (8.0f / 768.0f) - 0.5f;
    float sx = (j + 0.5f) * (8.0f / 768.0f) - 0.5f;
    float fy = floorf(sy), fx = floorf(sx);
    float wy = sy - fy, wx = sx - fx;
    int y0 = (int)fy, x0 = (int)fx;
    int y0c = min(max(y0, 0), 7), y1c = min(max(y0 + 1, 0), 7);
    int x0c = min(max(x0, 0), 7), x1c = min(max(x0 + 1, 0), 7);
    float v00 = seed[y0c * 8 + x0c], v01 = seed[y0c * 8 + x1c];
    float v10 = seed[y1c * 8 + x0c], v11 = seed[y1c * 8 + x1c];
    float top = v00 + wx * (v01 - v00);
    float bot = v10 + wx * (v11 - v10);
    out[idx] = top + wy * (bot - top);
}

// KFUSE residual iterations fused per launch; shrinking-halo LDS tiles.
// Channel-outer over a batch of B pixels per thread: B independent 9-FMA
// chains (ILP), weights amortized over B, one saturation branch per channel.
__global__ __launch_bounds__(NT, 4) void fused_steps(
        const float* __restrict__ xin, float* __restrict__ xout,
        const float* __restrict__ w1, const float* __restrict__ b1,
        const float* __restrict__ w2, const float* __restrict__ b2) {
    __shared__ float buf[2][ITY * ITX];   // 2 x 32x56 x 4B = 14.3 KB
    const int tid = threadIdx.x;
    const int bx = blockIdx.x % NBX, by = blockIdx.x / NBX;
    const int gx0 = bx * TX - KFUSE, gy0 = by * TY - KFUSE;

    // stage 56x32 input tile (zero outside image = conv 'SAME' zero pad)
    for (int p = tid; p < ITY * ITX; p += NT) {
        int r = p / ITX, c = p - r * ITX;
        int gy = gy0 + r, gx = gx0 + c;
        float v = 0.0f;
        if (gy >= 0 && gy < IMG && gx >= 0 && gx < IMG) v = xin[gy * IMG + gx];
        buf[0][p] = v;
    }
    __syncthreads();

    const float yinit = b2[0] * RES_SCALE;

#pragma unroll
    for (int j = 0; j < KFUSE; ++j) {
        const int SX = ITX - 2 - 2 * j;    // 54,52,50,48
        const int SY = ITY - 2 - 2 * j;    // 30,28,26,24
        const int off = j + 1;
        const int total = SX * SY;         // 1620,1456,1300,1152
        const int B = (total + NT - 1) / NT;  // 4,3,3,3 (compile-time)
        const float* src = &buf[j & 1][0];
        float* dst = &buf[(j & 1) ^ 1][0];

        int rr[4], cc[4];
        bool ok[4];
        float nb[4][9];
#pragma unroll
        for (int k = 0; k < B; ++k) {
            int p = tid + k * NT;
            ok[k] = p < total;
            if (!ok[k]) p = total - 1;     // clamp: duplicate of a valid pixel
            int q = p / SX;                // SX compile-time -> magic mul
            rr[k] = off + q;
            cc[k] = off + (p - q * SX);
            const float* s0 = &src[(rr[k] - 1) * ITX + cc[k] - 1];
            nb[k][0] = s0[0];           nb[k][1] = s0[1];           nb[k][2] = s0[2];
            nb[k][3] = s0[ITX];         nb[k][4] = s0[ITX + 1];     nb[k][5] = s0[ITX + 2];
            nb[k][6] = s0[2 * ITX];     nb[k][7] = s0[2 * ITX + 1]; nb[k][8] = s0[2 * ITX + 2];
        }
        float y[4];
#pragma unroll
        for (int k = 0; k < B; ++k) y[k] = yinit;

#pragma unroll
        for (int ch = 0; ch < 16; ++ch) {
            const float* wc = &w1[ch * 9];        // uniform -> s_load
            const float b1c = b1[ch];
            const float w2c = w2[ch] * RES_SCALE; // pre-scaled accumulate
            float a[4];
            float mn = 1e30f;
#pragma unroll
            for (int k = 0; k < B; ++k) {         // B independent FMA chains
                float t = b1c;
                t = fmaf(wc[0], nb[k][0], t);
                t = fmaf(wc[1], nb[k][1], t);
                t = fmaf(wc[2], nb[k][2], t);
                t = fmaf(wc[3], nb[k][3], t);
                t = fmaf(wc[4], nb[k][4], t);
                t = fmaf(wc[5], nb[k][5], t);
                t = fmaf(wc[6], nb[k][6], t);
                t = fmaf(wc[7], nb[k][7], t);
                t = fmaf(wc[8], nb[k][8], t);
                a[k] = t;
                mn = fminf(mn, fabsf(t));
            }
            // fp32 erf saturates exactly for |a|>5.66 -> relu path, one
            // wave-uniform branch per channel per B-pixel batch
            if (__all(mn > 5.7f)) {
#pragma unroll
                for (int k = 0; k < B; ++k)
                    y[k] = fmaf(w2c, fmaxf(a[k], 0.0f), y[k]);
            } else {
#pragma unroll
                for (int k = 0; k < B; ++k)
                    y[k] = fmaf(w2c, gelu_exact(a[k]), y[k]);
            }
        }

#pragma unroll
        for (int k = 0; k < B; ++k) {
            int gy = gy0 + rr[k], gx = gx0 + cc[k];
            bool inimg = (gy >= 0) && (gy < IMG) && (gx >= 0) && (gx < IMG);
            // ghost pixels outside image stay 0 every iteration (zero padding)
            float v = inimg ? nb[k][4] + y[k] : 0.0f;
            if (ok[k]) dst[rr[k] * ITX + cc[k]] = v;
        }
        __syncthreads();
    }

    // KFUSE even -> final state in buf[0]
    for (int p = tid; p < TY * TX; p += NT) {
        int r = p / TX, c = p - r * TX;
        xout[(gy0 + KFUSE + r) * IMG + (gx0 + KFUSE + c)] =
            buf[0][(KFUSE + r) * ITX + (KFUSE + c)];
    }
}

extern "C" void kernel_launch(void* const* d_in, const int* in_sizes, int n_in,
                              void* d_out, int out_size, void* d_ws, size_t ws_size,
                              hipStream_t stream) {
    const float* seed = (const float*)d_in[0];
    const float* w1   = (const float*)d_in[1];
    const float* b1   = (const float*)d_in[2];
    const float* w2   = (const float*)d_in[3];
    const float* b2   = (const float*)d_in[4];
    // d_in[5]/d_in[6] are rows/cols = 768/768 (fixed by setup_inputs)

    float* out = (float*)d_out;
    float* ws  = (float*)d_ws;   // second ping-pong buffer (2.36 MB)

    resize_bilinear<<<(IMG * IMG + 255) / 256, 256, 0, stream>>>(seed, out);

    float* a = out;
    float* b = ws;
    for (int it = 0; it < NITER; it += KFUSE) {   // 16 launches, even -> ends in d_out
        fused_steps<<<NBX * NBY, NT, 0, stream>>>(a, b, w1, b1, w2, b2);
        float* t = a; a = b; b = t;
    }
}